// Round 11
// baseline (169.421 us; speedup 1.0000x reference)
//
#include <hip/hip_runtime.h>
#include <math.h>

#define T_SEQ  2048
#define D_MODEL 512
#define NH     8
#define DK     64
#define NKB    32
#define BH     16
#define HK     512
#define NCH    2
#define CHB    16
#define LOG2E  1.44269504088896340736f
#define QSCALE (0.125f * LOG2E)

typedef unsigned int uint;
typedef unsigned short ushort;
typedef unsigned long long ull_t;
typedef __attribute__((ext_vector_type(8))) short bf16x8;
typedef __attribute__((ext_vector_type(4))) float f32x4;

// ---- workspace byte offsets (NCH=2 fixed; attS overlays dead Q planes) ----
#define QHI_B   (0ull)
#define QLO_B   (QHI_B + 4194304ull)     // [bh][t][dk] ushort
#define KHI_B   (QLO_B + 4194304ull)
#define KLO_B   (KHI_B + 4194304ull)
#define VTHI_B  (KLO_B + 4194304ull)     // [bh][dk][t] ushort
#define VTLO_B  (VTHI_B + 4194304ull)
#define WTHI_B  (VTLO_B + 4194304ull)    // [which][h][k][d] ushort, 1572864 B
#define WTLO_B  (WTHI_B + 1572864ull)
#define WOTHI_B (WTLO_B + 1572864ull)    // [d][hk] ushort, 524288 B
#define WOTLO_B (WOTHI_B + 524288ull)
#define ATTP_B  (WOTLO_B + 524288ull)    // NCH x [b][t][hk] f32 (8 MB each)
#define CHUNK_F 2097152ull
#define CHUNK_BYTES 8388608ull
#define STAT_F  (BH * T_SEQ)             // 32768 floats per (m|l|sc) chunk slot
#define MST_B   (ATTP_B + (ull_t)NCH * CHUNK_BYTES)
#define LST_B   (MST_B + (ull_t)NCH * STAT_F * 4ull)
#define SST_B   (LST_B + (ull_t)NCH * STAT_F * 4ull)
#define ATTSHI_B QHI_B                   // overlay on dead Q planes
#define ATTSLO_B QLO_B

// truncation split: hi = bit-trunc bf16 of x; lo = bit-trunc bf16 of (x - hi).
static __device__ __forceinline__ void tsplit2(float a, float b, uint& hi, uint& lo) {
    uint ua = __float_as_uint(a), ub = __float_as_uint(b);
    uint ha = ua & 0xFFFF0000u, hb = ub & 0xFFFF0000u;
    hi = (ha >> 16) | hb;
    float ra = a - __uint_as_float(ha);
    float rb = b - __uint_as_float(hb);
    lo = (__float_as_uint(ra) >> 16) | (__float_as_uint(rb) & 0xFFFF0000u);
}

// ---------------------------------------------------------------------------
// Kernel 0: weight prep (round-5 verbatim).
// ---------------------------------------------------------------------------
__global__ __launch_bounds__(256) void split_w(
    const float* __restrict__ Wq, const float* __restrict__ Wk,
    const float* __restrict__ Wv, const float* __restrict__ Wo,
    float* __restrict__ ws)
{
    uint* WTH = (uint*)((char*)ws + WTHI_B);
    uint* WTL = (uint*)((char*)ws + WTLO_B);
    uint* WOH = (uint*)((char*)ws + WOTHI_B);
    uint* WOL = (uint*)((char*)ws + WOTLO_B);
    const int gid = blockIdx.x * 256 + threadIdx.x;
    if (blockIdx.x < 1536) {
        const int d2 = gid & 255;
        const int k = (gid >> 8) & 63;
        const int h = (gid >> 14) & 7;
        const int which = gid >> 17;
        const float* W = (which == 0 ? Wq : (which == 1 ? Wk : Wv));
        const float* src = W + ((size_t)h * D_MODEL + 2 * d2) * DK + k;
        uint hi, lo;
        tsplit2(src[0], src[DK], hi, lo);
        const size_t o = (((size_t)(which * 8 + h) * 64 + k) * 512 + 2 * d2) >> 1;
        WTH[o] = hi; WTL[o] = lo;
    } else {
        const int o = gid - 1536 * 256;
        const int hk2 = o & 255;
        const int d = o >> 8;
        const float* src = Wo + (size_t)(2 * hk2) * D_MODEL + d;
        uint hi, lo;
        tsplit2(src[0], src[D_MODEL], hi, lo);
        const size_t oo = ((size_t)d * 512 + 2 * hk2) >> 1;
        WOH[oo] = hi; WOL[oo] = lo;
    }
}

// ---------------------------------------------------------------------------
// Kernel 1: QKV projections (round-5 verbatim).  grid (T/64, BH, 3).
// ---------------------------------------------------------------------------
__global__ __launch_bounds__(256) void proj_mfma(
    const float* __restrict__ query, const float* __restrict__ value,
    float* __restrict__ ws)
{
    const int which = blockIdx.z;
    const int bh = blockIdx.y, b = bh >> 3, h = bh & 7;
    const int t0 = blockIdx.x * 64;
    const float* X = (which == 0 ? query : value) + (size_t)b * T_SEQ * D_MODEL;
    const ushort* WtH = (const ushort*)((char*)ws + WTHI_B) + (size_t)(which * 8 + h) * 64 * 512;
    const ushort* WtL = (const ushort*)((char*)ws + WTLO_B) + (size_t)(which * 8 + h) * 64 * 512;

    __shared__ ushort BsH[64][64], BsL[64][64];

    const int tid = threadIdx.x, lane = tid & 63, w = tid >> 6;
    const int lr = lane & 15, lg = lane >> 4;
    const int sg = tid & 7, srow = tid >> 3;
    const int swz0 = (sg ^ (srow & 7)) * 8;
    const int c0s = (lg ^ (lr & 7)) * 8, c1s = c0s ^ 32;

    f32x4 acc[4];
#pragma unroll
    for (int i = 0; i < 4; ++i) acc[i] = (f32x4){0.f, 0.f, 0.f, 0.f};

    for (int d0 = 0; d0 < D_MODEL; d0 += 64) {
        __syncthreads();
        *(uint4*)&BsH[srow][swz0]      = *(const uint4*)&WtH[(size_t)srow * 512 + d0 + sg * 8];
        *(uint4*)&BsH[srow + 32][swz0] = *(const uint4*)&WtH[(size_t)(srow + 32) * 512 + d0 + sg * 8];
        *(uint4*)&BsL[srow][swz0]      = *(const uint4*)&WtL[(size_t)srow * 512 + d0 + sg * 8];
        *(uint4*)&BsL[srow + 32][swz0] = *(const uint4*)&WtL[(size_t)(srow + 32) * 512 + d0 + sg * 8];
        __syncthreads();

        const float* xr = &X[(size_t)(t0 + w * 16 + lr) * D_MODEL + d0];
        float x0[8], x1[8];
        *(float4*)&x0[0] = *(const float4*)(xr + lg * 8);
        *(float4*)&x0[4] = *(const float4*)(xr + lg * 8 + 4);
        *(float4*)&x1[0] = *(const float4*)(xr + 32 + lg * 8);
        *(float4*)&x1[4] = *(const float4*)(xr + 32 + lg * 8 + 4);
        union { bf16x8 v; uint u[4]; } xh0, xl0, xh1, xl1;
#pragma unroll
        for (int i = 0; i < 4; ++i) {
            tsplit2(x0[2 * i], x0[2 * i + 1], xh0.u[i], xl0.u[i]);
            tsplit2(x1[2 * i], x1[2 * i + 1], xh1.u[i], xl1.u[i]);
        }

#pragma unroll
        for (int m2 = 0; m2 < 4; ++m2) {
            const int row = m2 * 16 + lr;
            bf16x8 wh0 = *(const bf16x8*)&BsH[row][c0s];
            bf16x8 wh1 = *(const bf16x8*)&BsH[row][c1s];
            bf16x8 wl0 = *(const bf16x8*)&BsL[row][c0s];
            bf16x8 wl1 = *(const bf16x8*)&BsL[row][c1s];
            f32x4 a = acc[m2];
            if (which < 2) {
                a = __builtin_amdgcn_mfma_f32_16x16x32_bf16(wh0, xh0.v, a, 0, 0, 0);
                a = __builtin_amdgcn_mfma_f32_16x16x32_bf16(wh1, xh1.v, a, 0, 0, 0);
                a = __builtin_amdgcn_mfma_f32_16x16x32_bf16(wh0, xl0.v, a, 0, 0, 0);
                a = __builtin_amdgcn_mfma_f32_16x16x32_bf16(wh1, xl1.v, a, 0, 0, 0);
                a = __builtin_amdgcn_mfma_f32_16x16x32_bf16(wl0, xh0.v, a, 0, 0, 0);
                a = __builtin_amdgcn_mfma_f32_16x16x32_bf16(wl1, xh1.v, a, 0, 0, 0);
            } else {
                a = __builtin_amdgcn_mfma_f32_16x16x32_bf16(xh0.v, wh0, a, 0, 0, 0);
                a = __builtin_amdgcn_mfma_f32_16x16x32_bf16(xh1.v, wh1, a, 0, 0, 0);
                a = __builtin_amdgcn_mfma_f32_16x16x32_bf16(xl0.v, wh0, a, 0, 0, 0);
                a = __builtin_amdgcn_mfma_f32_16x16x32_bf16(xl1.v, wh1, a, 0, 0, 0);
                a = __builtin_amdgcn_mfma_f32_16x16x32_bf16(xh0.v, wl0, a, 0, 0, 0);
                a = __builtin_amdgcn_mfma_f32_16x16x32_bf16(xh1.v, wl1, a, 0, 0, 0);
            }
            acc[m2] = a;
        }
    }

    if (which < 2) {
        ushort* OH = (ushort*)((char*)ws + (which == 0 ? QHI_B : KHI_B)) + (size_t)bh * T_SEQ * DK;
        ushort* OL = (ushort*)((char*)ws + (which == 0 ? QLO_B : KLO_B)) + (size_t)bh * T_SEQ * DK;
        const float scl = (which == 0) ? QSCALE : 1.0f;
#pragma unroll
        for (int m2 = 0; m2 < 4; ++m2) {
            uint h0, l0, h1, l1;
            tsplit2(acc[m2][0] * scl, acc[m2][1] * scl, h0, l0);
            tsplit2(acc[m2][2] * scl, acc[m2][3] * scl, h1, l1);
            const size_t addr = (size_t)(t0 + w * 16 + lr) * DK + m2 * 16 + lg * 4;
            *(uint2*)&OH[addr] = make_uint2(h0, h1);
            *(uint2*)&OL[addr] = make_uint2(l0, l1);
        }
    } else {
        ushort* OH = (ushort*)((char*)ws + VTHI_B) + (size_t)bh * DK * T_SEQ;
        ushort* OL = (ushort*)((char*)ws + VTLO_B) + (size_t)bh * DK * T_SEQ;
#pragma unroll
        for (int n2 = 0; n2 < 4; ++n2) {
            uint h0, l0, h1, l1;
            tsplit2(acc[n2][0], acc[n2][1], h0, l0);
            tsplit2(acc[n2][2], acc[n2][3], h1, l1);
            const size_t addr = (size_t)(n2 * 16 + lr) * T_SEQ + t0 + w * 16 + lg * 4;
            *(uint2*)&OH[addr] = make_uint2(h0, h1);
            *(uint2*)&OL[addr] = make_uint2(l0, l1);
        }
    }
}

// ---------------------------------------------------------------------------
// Kernel 2: flash attention.  Round-5 structure, but P OVERLAYS the K tile
// (K is dead after QK; P written after a post-QK barrier).  LDS 48->32 KB
// -> up to 5 blocks/CU co-resident; latency chain hides across blocks.
// grid (T/64, BH, NCH), block 256.
// ---------------------------------------------------------------------------
__global__ __launch_bounds__(256, 4) void attn_fwd(
    const int* __restrict__ ls_ptr, float* __restrict__ ws)
{
    const int bh = blockIdx.y, b = bh >> 3, h = bh & 7;
    const int mtype = h >> 1;
    const int row0 = blockIdx.x * 64, rb = row0 >> 6;
    const int chunk = blockIdx.z;
    const int ls = *ls_ptr;

    float* mrow = (float*)((char*)ws + MST_B) + ((size_t)chunk * BH + bh) * T_SEQ;
    float* lrow = (float*)((char*)ws + LST_B) + ((size_t)chunk * BH + bh) * T_SEQ;

    int klo = 0, khi = NKB - 1;
    if (mtype == 1) {
        int l2 = row0 - ls; if (l2 < 0) l2 = 0;
        int h2 = row0 + 63 + ls; if (h2 > T_SEQ - 1) h2 = T_SEQ - 1;
        klo = l2 >> 6; khi = h2 >> 6;
    } else if (mtype == 2) {
        klo = rb;
    } else if (mtype == 3) {
        khi = rb;
    }
    const int kb0 = klo > chunk * CHB ? klo : chunk * CHB;
    const int kb1 = khi < chunk * CHB + CHB - 1 ? khi : chunk * CHB + CHB - 1;

    const int tid = threadIdx.x;
    if (kb0 > kb1) {
        if (tid < 64) { mrow[row0 + tid] = -INFINITY; lrow[row0 + tid] = 0.f; }
        return;
    }

    const ushort* Qh_g = (const ushort*)((char*)ws + QHI_B) + (size_t)bh * T_SEQ * DK;
    const ushort* Ql_g = (const ushort*)((char*)ws + QLO_B) + (size_t)bh * T_SEQ * DK;
    const ushort* Kh_g = (const ushort*)((char*)ws + KHI_B) + (size_t)bh * T_SEQ * DK;
    const ushort* Kl_g = (const ushort*)((char*)ws + KLO_B) + (size_t)bh * T_SEQ * DK;
    const ushort* Vh_g = (const ushort*)((char*)ws + VTHI_B) + (size_t)bh * DK * T_SEQ;
    const ushort* Vl_g = (const ushort*)((char*)ws + VTLO_B) + (size_t)bh * DK * T_SEQ;
    float* attP = (float*)((char*)ws + ATTP_B) + (size_t)chunk * CHUNK_F;

    // K tile and P tile SHARE storage (K dead after QK; barrier in between).
    __shared__ ushort KPhS[64][64], KPlS[64][64];
    __shared__ ushort VhS[64][64], VlS[64][64];

    const int lane = tid & 63, w = tid >> 6;
    const int lr = lane & 15, lg = lane >> 4;
    const int sg = tid & 7, srow = tid >> 3;
    const int swz0 = (sg ^ (srow & 7)) * 8;
    const int c0s = (lg ^ (lr & 7)) * 8, c1s = c0s ^ 32;

    // Q fragments (loop-invariant, from global)
    const ushort* qh = Qh_g + (size_t)(row0 + w * 16 + lr) * DK;
    const ushort* ql = Ql_g + (size_t)(row0 + w * 16 + lr) * DK;
    const bf16x8 bqh0 = *(const bf16x8*)(qh + lg * 8);
    const bf16x8 bqh1 = *(const bf16x8*)(qh + 32 + lg * 8);
    const bf16x8 bql0 = *(const bf16x8*)(ql + lg * 8);
    const bf16x8 bql1 = *(const bf16x8*)(ql + 32 + lg * 8);

    float m_i = -INFINITY, l_i = 0.f;
    f32x4 oacc[4];
#pragma unroll
    for (int i = 0; i < 4; ++i) oacc[i] = (f32x4){0.f, 0.f, 0.f, 0.f};

    uint4 kr0, kr1, kr2, kr3, vr0, vr1, vr2, vr3;
    kr0 = *(const uint4*)&Kh_g[(size_t)(kb0 * 64 + srow) * DK + sg * 8];
    kr1 = *(const uint4*)&Kh_g[(size_t)(kb0 * 64 + srow + 32) * DK + sg * 8];
    kr2 = *(const uint4*)&Kl_g[(size_t)(kb0 * 64 + srow) * DK + sg * 8];
    kr3 = *(const uint4*)&Kl_g[(size_t)(kb0 * 64 + srow + 32) * DK + sg * 8];
    vr0 = *(const uint4*)&Vh_g[(size_t)srow * T_SEQ + kb0 * 64 + sg * 8];
    vr1 = *(const uint4*)&Vh_g[(size_t)(srow + 32) * T_SEQ + kb0 * 64 + sg * 8];
    vr2 = *(const uint4*)&Vl_g[(size_t)srow * T_SEQ + kb0 * 64 + sg * 8];
    vr3 = *(const uint4*)&Vl_g[(size_t)(srow + 32) * T_SEQ + kb0 * 64 + sg * 8];

    for (int kb = kb0; kb <= kb1; ++kb) {
        __syncthreads();   // prev iter's PV (P and V reads) complete
        *(uint4*)&KPhS[srow][swz0] = kr0; *(uint4*)&KPhS[srow + 32][swz0] = kr1;
        *(uint4*)&KPlS[srow][swz0] = kr2; *(uint4*)&KPlS[srow + 32][swz0] = kr3;
        *(uint4*)&VhS[srow][swz0] = vr0; *(uint4*)&VhS[srow + 32][swz0] = vr1;
        *(uint4*)&VlS[srow][swz0] = vr2; *(uint4*)&VlS[srow + 32][swz0] = vr3;
        if (kb < kb1) {
            const int kn = kb + 1;
            kr0 = *(const uint4*)&Kh_g[(size_t)(kn * 64 + srow) * DK + sg * 8];
            kr1 = *(const uint4*)&Kh_g[(size_t)(kn * 64 + srow + 32) * DK + sg * 8];
            kr2 = *(const uint4*)&Kl_g[(size_t)(kn * 64 + srow) * DK + sg * 8];
            kr3 = *(const uint4*)&Kl_g[(size_t)(kn * 64 + srow + 32) * DK + sg * 8];
            vr0 = *(const uint4*)&Vh_g[(size_t)srow * T_SEQ + kn * 64 + sg * 8];
            vr1 = *(const uint4*)&Vh_g[(size_t)(srow + 32) * T_SEQ + kn * 64 + sg * 8];
            vr2 = *(const uint4*)&Vl_g[(size_t)srow * T_SEQ + kn * 64 + sg * 8];
            vr3 = *(const uint4*)&Vl_g[(size_t)(srow + 32) * T_SEQ + kn * 64 + sg * 8];
        }
        __syncthreads();   // staging visible

        // ---- QK: S^T[s][t] = K . Q^T ----
        f32x4 sacc[4];
#pragma unroll
        for (int m = 0; m < 4; ++m) {
            const int row = m * 16 + lr;
            bf16x8 ah0 = *(const bf16x8*)&KPhS[row][c0s];
            bf16x8 ah1 = *(const bf16x8*)&KPhS[row][c1s];
            bf16x8 al0 = *(const bf16x8*)&KPlS[row][c0s];
            bf16x8 al1 = *(const bf16x8*)&KPlS[row][c1s];
            f32x4 a = (f32x4){0.f, 0.f, 0.f, 0.f};
            a = __builtin_amdgcn_mfma_f32_16x16x32_bf16(ah0, bqh0, a, 0, 0, 0);
            a = __builtin_amdgcn_mfma_f32_16x16x32_bf16(ah1, bqh1, a, 0, 0, 0);
            a = __builtin_amdgcn_mfma_f32_16x16x32_bf16(ah0, bql0, a, 0, 0, 0);
            a = __builtin_amdgcn_mfma_f32_16x16x32_bf16(ah1, bql1, a, 0, 0, 0);
            a = __builtin_amdgcn_mfma_f32_16x16x32_bf16(al0, bqh0, a, 0, 0, 0);
            a = __builtin_amdgcn_mfma_f32_16x16x32_bf16(al1, bqh1, a, 0, 0, 0);
            sacc[m] = a;
        }

        // ---- mask + online softmax (base 2; t = lane&15) ----
        const int t_glob = row0 + w * 16 + lr;
        const bool needmask = (mtype == 1) || ((mtype >= 2) && (kb == rb));
        float p[4][4];
        float vmax = -INFINITY;
#pragma unroll
        for (int m = 0; m < 4; ++m)
#pragma unroll
            for (int r = 0; r < 4; ++r) {
                float x = sacc[m][r];
                if (needmask) {
                    int s_glob = kb * 64 + m * 16 + lg * 4 + r;
                    bool keep;
                    if (mtype == 1) keep = (t_glob - s_glob <= ls) && (s_glob - t_glob <= ls);
                    else if (mtype == 2) keep = (s_glob >= t_glob);
                    else keep = (s_glob <= t_glob);
                    if (!keep) x = -INFINITY;
                }
                p[m][r] = x;
                vmax = fmaxf(vmax, x);
            }
        vmax = fmaxf(vmax, __shfl_xor(vmax, 16, 64));
        vmax = fmaxf(vmax, __shfl_xor(vmax, 32, 64));
        const float mn = fmaxf(m_i, vmax);
        float factor = 1.f, psum = 0.f;
        if (mn == -INFINITY) {
#pragma unroll
            for (int m = 0; m < 4; ++m)
#pragma unroll
                for (int r = 0; r < 4; ++r) p[m][r] = 0.f;
        } else {
            factor = exp2f(m_i - mn);
            m_i = mn;
#pragma unroll
            for (int m = 0; m < 4; ++m)
#pragma unroll
                for (int r = 0; r < 4; ++r) {
                    p[m][r] = exp2f(p[m][r] - mn);
                    psum += p[m][r];
                }
        }
        psum += __shfl_xor(psum, 16, 64);
        psum += __shfl_xor(psum, 32, 64);
        l_i = l_i * factor + psum;

        __syncthreads();   // all waves' QK reads of K done; P may overwrite

        // ---- store P over the dead K tile (t-major, swizzled) ----
#pragma unroll
        for (int m = 0; m < 4; ++m) {
            uint ph01, pl01, ph23, pl23;
            tsplit2(p[m][0], p[m][1], ph01, pl01);
            tsplit2(p[m][2], p[m][3], ph23, pl23);
            const int pg = (((m * 2 + (lg >> 1)) ^ (lr & 7)) * 8) + (lg & 1) * 4;
            *(uint2*)&KPhS[w * 16 + lr][pg] = make_uint2(ph01, ph23);
            *(uint2*)&KPlS[w * 16 + lr][pg] = make_uint2(pl01, pl23);
        }

        // ---- rescale O ----
        float fr[4];
#pragma unroll
        for (int r = 0; r < 4; ++r) fr[r] = __shfl(factor, lg * 4 + r, 64);
#pragma unroll
        for (int n2 = 0; n2 < 4; ++n2)
#pragma unroll
            for (int r = 0; r < 4; ++r) oacc[n2][r] *= fr[r];

        // ---- PV: O[t][dk] += P V  (P rows are wave-private; no barrier) ----
        const bf16x8 aph0 = *(const bf16x8*)&KPhS[w * 16 + lr][c0s];
        const bf16x8 aph1 = *(const bf16x8*)&KPhS[w * 16 + lr][c1s];
        const bf16x8 apl0 = *(const bf16x8*)&KPlS[w * 16 + lr][c0s];
        const bf16x8 apl1 = *(const bf16x8*)&KPlS[w * 16 + lr][c1s];
#pragma unroll
        for (int n2 = 0; n2 < 4; ++n2) {
            const int row = n2 * 16 + lr;
            bf16x8 bh0 = *(const bf16x8*)&VhS[row][c0s];
            bf16x8 bh1 = *(const bf16x8*)&VhS[row][c1s];
            bf16x8 bl0 = *(const bf16x8*)&VlS[row][c0s];
            bf16x8 bl1 = *(const bf16x8*)&VlS[row][c1s];
            f32x4 a = oacc[n2];
            a = __builtin_amdgcn_mfma_f32_16x16x32_bf16(aph0, bh0, a, 0, 0, 0);
            a = __builtin_amdgcn_mfma_f32_16x16x32_bf16(aph1, bh1, a, 0, 0, 0);
            a = __builtin_amdgcn_mfma_f32_16x16x32_bf16(aph0, bl0, a, 0, 0, 0);
            a = __builtin_amdgcn_mfma_f32_16x16x32_bf16(aph1, bl1, a, 0, 0, 0);
            a = __builtin_amdgcn_mfma_f32_16x16x32_bf16(apl0, bh0, a, 0, 0, 0);
            a = __builtin_amdgcn_mfma_f32_16x16x32_bf16(apl1, bh1, a, 0, 0, 0);
            oacc[n2] = a;
        }
    }

#pragma unroll
    for (int n2 = 0; n2 < 4; ++n2)
#pragma unroll
        for (int r = 0; r < 4; ++r) {
            int t = row0 + w * 16 + lg * 4 + r;
            attP[((size_t)b * T_SEQ + t) * HK + h * DK + n2 * 16 + lr] = oacc[n2][r];
        }
    if (lg == 0) {
        mrow[row0 + w * 16 + lr] = m_i;
        lrow[row0 + w * 16 + lr] = l_i;
    }
}

// ---------------------------------------------------------------------------
// Kernel 3: per-(b,h) reduce of (m,l) over chunks -> scale (base-2 domain).
// ---------------------------------------------------------------------------
__global__ __launch_bounds__(256) void softmax_stats(float* __restrict__ ws)
{
    const int bh = blockIdx.x;
    float* mbase = (float*)((char*)ws + MST_B);
    float* lbase = (float*)((char*)ws + LST_B);
    float* sbase = (float*)((char*)ws + SST_B);

    __shared__ float red[256];
    const int tid = threadIdx.x;
    const int n = NCH * T_SEQ;

    float mymax = -INFINITY;
    for (int i = tid; i < n; i += 256) {
        int c = i >> 11, t = i & 2047;
        mymax = fmaxf(mymax, mbase[((size_t)c * BH + bh) * T_SEQ + t]);
    }
    red[tid] = mymax; __syncthreads();
    for (int s = 128; s > 0; s >>= 1) {
        if (tid < s) red[tid] = fmaxf(red[tid], red[tid + s]);
        __syncthreads();
    }
    const float M = red[0]; __syncthreads();

    float mysum = 0.f;
    for (int i = tid; i < n; i += 256) {
        int c = i >> 11, t = i & 2047;
        size_t idx = ((size_t)c * BH + bh) * T_SEQ + t;
        mysum += lbase[idx] * exp2f(mbase[idx] - M);
    }
    red[tid] = mysum; __syncthreads();
    for (int s = 128; s > 0; s >>= 1) {
        if (tid < s) red[tid] += red[tid + s];
        __syncthreads();
    }
    const float Z = red[0];

    for (int i = tid; i < n; i += 256) {
        int c = i >> 11, t = i & 2047;
        size_t idx = ((size_t)c * BH + bh) * T_SEQ + t;
        sbase[idx] = exp2f(mbase[idx] - M) / Z;
    }
}

// ---------------------------------------------------------------------------
// Kernel 4: attS(bf16 hi/lo, overlaid on dead Q planes) =
//           sum_c attP[c] * scale[c].  grid 2048 x 256.
// ---------------------------------------------------------------------------
__global__ __launch_bounds__(256) void reduce_split(float* __restrict__ ws)
{
    const size_t flat = ((size_t)blockIdx.x * 256 + threadIdx.x) * 4;
    const float* attP = (const float*)((char*)ws + ATTP_B);
    const float* sc = (const float*)((char*)ws + SST_B);
    ushort* SH = (ushort*)((char*)ws + ATTSHI_B);
    ushort* SL = (ushort*)((char*)ws + ATTSLO_B);

    const int hk = (int)(flat & (HK - 1));
    const size_t bt = flat / HK;
    const int b = (int)(bt >> 11), t = (int)(bt & 2047);
    const int h = hk >> 6;

    float4 acc = make_float4(0.f, 0.f, 0.f, 0.f);
    for (int c = 0; c < NCH; ++c) {
        float4 a = *(const float4*)&attP[(size_t)c * CHUNK_F + flat];
        float s = sc[((size_t)c * BH + b * NH + h) * T_SEQ + t];
        acc.x = fmaf(a.x, s, acc.x); acc.y = fmaf(a.y, s, acc.y);
        acc.z = fmaf(a.z, s, acc.z); acc.w = fmaf(a.w, s, acc.w);
    }
    uint h0, l0, h1, l1;
    tsplit2(acc.x, acc.y, h0, l0);
    tsplit2(acc.z, acc.w, h1, l1);
    *(uint2*)&SH[flat] = make_uint2(h0, h1);
    *(uint2*)&SL[flat] = make_uint2(l0, l1);
}

// ---------------------------------------------------------------------------
// Kernel 5: out = attS . Wo (round-5 verbatim; attS at Q-plane offsets).
// grid (D/64, B*T/64), block 256.
// ---------------------------------------------------------------------------
__global__ __launch_bounds__(256) void out_proj_mfma(
    float* __restrict__ ws, float* __restrict__ out)
{
    const int d0 = blockIdx.x * 64;
    const int r0 = blockIdx.y * 64;
    const ushort* AH = (const ushort*)((char*)ws + ATTSHI_B);
    const ushort* AL = (const ushort*)((char*)ws + ATTSLO_B);
    const ushort* WoH = (const ushort*)((char*)ws + WOTHI_B);
    const ushort* WoL = (const ushort*)((char*)ws + WOTLO_B);

    __shared__ ushort BsH[64][64], BsL[64][64];

    const int tid = threadIdx.x, lane = tid & 63, w = tid >> 6;
    const int lr = lane & 15, lg = lane >> 4;
    const int sg = tid & 7, srow = tid >> 3;
    const int swz0 = (sg ^ (srow & 7)) * 8;
    const int c0s = (lg ^ (lr & 7)) * 8, c1s = c0s ^ 32;

    f32x4 acc[4];
#pragma unroll
    for (int i = 0; i < 4; ++i) acc[i] = (f32x4){0.f, 0.f, 0.f, 0.f};

    for (int k0 = 0; k0 < HK; k0 += 64) {
        __syncthreads();
        *(uint4*)&BsH[srow][swz0]      = *(const uint4*)&WoH[(size_t)(d0 + srow) * HK + k0 + sg * 8];
        *(uint4*)&BsH[srow + 32][swz0] = *(const uint4*)&WoH[(size_t)(d0 + srow + 32) * HK + k0 + sg * 8];
        *(uint4*)&BsL[srow][swz0]      = *(const uint4*)&WoL[(size_t)(d0 + srow) * HK + k0 + sg * 8];
        *(uint4*)&BsL[srow + 32][swz0] = *(const uint4*)&WoL[(size_t)(d0 + srow + 32) * HK + k0 + sg * 8];
        __syncthreads();

        const ushort* ar = AH + (size_t)(r0 + w * 16 + lr) * HK + k0;
        const ushort* al = AL + (size_t)(r0 + w * 16 + lr) * HK + k0;
        bf16x8 ah0 = *(const bf16x8*)(ar + lg * 8);
        bf16x8 ah1 = *(const bf16x8*)(ar + 32 + lg * 8);
        bf16x8 al0 = *(const bf16x8*)(al + lg * 8);
        bf16x8 al1 = *(const bf16x8*)(al + 32 + lg * 8);

#pragma unroll
        for (int n2 = 0; n2 < 4; ++n2) {
            const int row = n2 * 16 + lr;
            bf16x8 wh0 = *(const bf16x8*)&BsH[row][c0s];
            bf16x8 wh1 = *(const bf16x8*)&BsH[row][c1s];
            bf16x8 wl0 = *(const bf16x8*)&BsL[row][c0s];
            bf16x8 wl1 = *(const bf16x8*)&BsL[row][c1s];
            f32x4 a = acc[n2];
            a = __builtin_amdgcn_mfma_f32_16x16x32_bf16(ah0, wh0, a, 0, 0, 0);
            a = __builtin_amdgcn_mfma_f32_16x16x32_bf16(ah1, wh1, a, 0, 0, 0);
            a = __builtin_amdgcn_mfma_f32_16x16x32_bf16(ah0, wl0, a, 0, 0, 0);
            a = __builtin_amdgcn_mfma_f32_16x16x32_bf16(ah1, wl1, a, 0, 0, 0);
            a = __builtin_amdgcn_mfma_f32_16x16x32_bf16(al0, wh0, a, 0, 0, 0);
            a = __builtin_amdgcn_mfma_f32_16x16x32_bf16(al1, wh1, a, 0, 0, 0);
            acc[n2] = a;
        }
    }

#pragma unroll
    for (int n2 = 0; n2 < 4; ++n2)
#pragma unroll
        for (int i = 0; i < 4; ++i)
            out[(size_t)(r0 + w * 16 + lg * 4 + i) * D_MODEL + d0 + n2 * 16 + lr] = acc[n2][i];
}

// ---------------------------------------------------------------------------
extern "C" void kernel_launch(void* const* d_in, const int* in_sizes, int n_in,
                              void* d_out, int out_size, void* d_ws, size_t ws_size,
                              hipStream_t stream)
{
    const float* query = (const float*)d_in[0];
    const float* value = (const float*)d_in[1];
    const float* Wq = (const float*)d_in[2];
    const float* Wk = (const float*)d_in[3];
    const float* Wv = (const float*)d_in[4];
    const float* Wo = (const float*)d_in[5];
    const int* ls = (const int*)d_in[6];
    float* out = (float*)d_out;
    float* ws = (float*)d_ws;

    split_w<<<dim3(2048), 256, 0, stream>>>(Wq, Wk, Wv, Wo, ws);

    proj_mfma<<<dim3(T_SEQ / 64, BH, 3), 256, 0, stream>>>(query, value, ws);

    attn_fwd<<<dim3(T_SEQ / 64, BH, NCH), 256, 0, stream>>>(ls, ws);

    softmax_stats<<<dim3(BH), 256, 0, stream>>>(ws);

    reduce_split<<<dim3(2 * T_SEQ * HK / 1024), 256, 0, stream>>>(ws);

    out_proj_mfma<<<dim3(D_MODEL / 64, 2 * T_SEQ / 64), 256, 0, stream>>>(ws, out);
}

// Round 12
// 144.265 us; speedup vs baseline: 1.1744x; 1.1744x over previous
//
#include <hip/hip_runtime.h>
#include <math.h>

#define T_SEQ  2048
#define D_MODEL 512
#define NH     8
#define DK     64
#define NKB    32
#define BH     16
#define HK     512
#define NCH    2
#define CHB    16
#define LOG2E  1.44269504088896340736f
#define QSCALE (0.125f * LOG2E)

typedef unsigned int uint;
typedef unsigned short ushort;
typedef unsigned long long ull_t;
typedef __attribute__((ext_vector_type(8))) short bf16x8;
typedef __attribute__((ext_vector_type(4))) float f32x4;

// ---- workspace byte offsets (NCH=2 fixed) ----
#define QHI_B   (0ull)
#define QLO_B   (QHI_B + 4194304ull)     // [bh][t][dk] ushort
#define KHI_B   (QLO_B + 4194304ull)
#define KLO_B   (KHI_B + 4194304ull)
#define VTHI_B  (KLO_B + 4194304ull)     // [bh][dk][t] ushort
#define VTLO_B  (VTHI_B + 4194304ull)
#define WTHI_B  (VTLO_B + 4194304ull)    // [which][h][k][d] ushort, 1572864 B
#define WTLO_B  (WTHI_B + 1572864ull)
#define WOTHI_B (WTLO_B + 1572864ull)    // [d][hk] ushort, 524288 B
#define WOTLO_B (WOTHI_B + 524288ull)
#define ATTP_B  (WOTLO_B + 524288ull)    // NCH x [b][t][hk] f32 (8 MB each)
#define CHUNK_F 2097152ull
#define CHUNK_BYTES 8388608ull
#define STAT_F  (BH * T_SEQ)
#define MST_B   (ATTP_B + (ull_t)NCH * CHUNK_BYTES)
#define LST_B   (MST_B + (ull_t)NCH * STAT_F * 4ull)
#define SST_B   (LST_B + (ull_t)NCH * STAT_F * 4ull)

// truncation split: hi = bit-trunc bf16 of x; lo = bit-trunc bf16 of (x - hi).
static __device__ __forceinline__ void tsplit2(float a, float b, uint& hi, uint& lo) {
    uint ua = __float_as_uint(a), ub = __float_as_uint(b);
    uint ha = ua & 0xFFFF0000u, hb = ub & 0xFFFF0000u;
    hi = (ha >> 16) | hb;
    float ra = a - __uint_as_float(ha);
    float rb = b - __uint_as_float(hb);
    lo = (__float_as_uint(ra) >> 16) | (__float_as_uint(rb) & 0xFFFF0000u);
}

// ---------------------------------------------------------------------------
// Kernel 0: weight prep (round-5 verbatim).
// ---------------------------------------------------------------------------
__global__ __launch_bounds__(256) void split_w(
    const float* __restrict__ Wq, const float* __restrict__ Wk,
    const float* __restrict__ Wv, const float* __restrict__ Wo,
    float* __restrict__ ws)
{
    uint* WTH = (uint*)((char*)ws + WTHI_B);
    uint* WTL = (uint*)((char*)ws + WTLO_B);
    uint* WOH = (uint*)((char*)ws + WOTHI_B);
    uint* WOL = (uint*)((char*)ws + WOTLO_B);
    const int gid = blockIdx.x * 256 + threadIdx.x;
    if (blockIdx.x < 1536) {
        const int d2 = gid & 255;
        const int k = (gid >> 8) & 63;
        const int h = (gid >> 14) & 7;
        const int which = gid >> 17;
        const float* W = (which == 0 ? Wq : (which == 1 ? Wk : Wv));
        const float* src = W + ((size_t)h * D_MODEL + 2 * d2) * DK + k;
        uint hi, lo;
        tsplit2(src[0], src[DK], hi, lo);
        const size_t o = (((size_t)(which * 8 + h) * 64 + k) * 512 + 2 * d2) >> 1;
        WTH[o] = hi; WTL[o] = lo;
    } else {
        const int o = gid - 1536 * 256;
        const int hk2 = o & 255;
        const int d = o >> 8;
        const float* src = Wo + (size_t)(2 * hk2) * D_MODEL + d;
        uint hi, lo;
        tsplit2(src[0], src[D_MODEL], hi, lo);
        const size_t oo = ((size_t)d * 512 + 2 * hk2) >> 1;
        WOH[oo] = hi; WOL[oo] = lo;
    }
}

// ---------------------------------------------------------------------------
// Kernel 1: QKV projections (round-5 verbatim).  grid (T/64, BH, 3).
// ---------------------------------------------------------------------------
__global__ __launch_bounds__(256) void proj_mfma(
    const float* __restrict__ query, const float* __restrict__ value,
    float* __restrict__ ws)
{
    const int which = blockIdx.z;
    const int bh = blockIdx.y, b = bh >> 3, h = bh & 7;
    const int t0 = blockIdx.x * 64;
    const float* X = (which == 0 ? query : value) + (size_t)b * T_SEQ * D_MODEL;
    const ushort* WtH = (const ushort*)((char*)ws + WTHI_B) + (size_t)(which * 8 + h) * 64 * 512;
    const ushort* WtL = (const ushort*)((char*)ws + WTLO_B) + (size_t)(which * 8 + h) * 64 * 512;

    __shared__ ushort BsH[64][64], BsL[64][64];

    const int tid = threadIdx.x, lane = tid & 63, w = tid >> 6;
    const int lr = lane & 15, lg = lane >> 4;
    const int sg = tid & 7, srow = tid >> 3;
    const int swz0 = (sg ^ (srow & 7)) * 8;
    const int c0s = (lg ^ (lr & 7)) * 8, c1s = c0s ^ 32;

    f32x4 acc[4];
#pragma unroll
    for (int i = 0; i < 4; ++i) acc[i] = (f32x4){0.f, 0.f, 0.f, 0.f};

    for (int d0 = 0; d0 < D_MODEL; d0 += 64) {
        __syncthreads();
        *(uint4*)&BsH[srow][swz0]      = *(const uint4*)&WtH[(size_t)srow * 512 + d0 + sg * 8];
        *(uint4*)&BsH[srow + 32][swz0] = *(const uint4*)&WtH[(size_t)(srow + 32) * 512 + d0 + sg * 8];
        *(uint4*)&BsL[srow][swz0]      = *(const uint4*)&WtL[(size_t)srow * 512 + d0 + sg * 8];
        *(uint4*)&BsL[srow + 32][swz0] = *(const uint4*)&WtL[(size_t)(srow + 32) * 512 + d0 + sg * 8];
        __syncthreads();

        const float* xr = &X[(size_t)(t0 + w * 16 + lr) * D_MODEL + d0];
        float x0[8], x1[8];
        *(float4*)&x0[0] = *(const float4*)(xr + lg * 8);
        *(float4*)&x0[4] = *(const float4*)(xr + lg * 8 + 4);
        *(float4*)&x1[0] = *(const float4*)(xr + 32 + lg * 8);
        *(float4*)&x1[4] = *(const float4*)(xr + 32 + lg * 8 + 4);
        union { bf16x8 v; uint u[4]; } xh0, xl0, xh1, xl1;
#pragma unroll
        for (int i = 0; i < 4; ++i) {
            tsplit2(x0[2 * i], x0[2 * i + 1], xh0.u[i], xl0.u[i]);
            tsplit2(x1[2 * i], x1[2 * i + 1], xh1.u[i], xl1.u[i]);
        }

#pragma unroll
        for (int m2 = 0; m2 < 4; ++m2) {
            const int row = m2 * 16 + lr;
            bf16x8 wh0 = *(const bf16x8*)&BsH[row][c0s];
            bf16x8 wh1 = *(const bf16x8*)&BsH[row][c1s];
            bf16x8 wl0 = *(const bf16x8*)&BsL[row][c0s];
            bf16x8 wl1 = *(const bf16x8*)&BsL[row][c1s];
            f32x4 a = acc[m2];
            if (which < 2) {
                a = __builtin_amdgcn_mfma_f32_16x16x32_bf16(wh0, xh0.v, a, 0, 0, 0);
                a = __builtin_amdgcn_mfma_f32_16x16x32_bf16(wh1, xh1.v, a, 0, 0, 0);
                a = __builtin_amdgcn_mfma_f32_16x16x32_bf16(wh0, xl0.v, a, 0, 0, 0);
                a = __builtin_amdgcn_mfma_f32_16x16x32_bf16(wh1, xl1.v, a, 0, 0, 0);
                a = __builtin_amdgcn_mfma_f32_16x16x32_bf16(wl0, xh0.v, a, 0, 0, 0);
                a = __builtin_amdgcn_mfma_f32_16x16x32_bf16(wl1, xh1.v, a, 0, 0, 0);
            } else {
                a = __builtin_amdgcn_mfma_f32_16x16x32_bf16(xh0.v, wh0, a, 0, 0, 0);
                a = __builtin_amdgcn_mfma_f32_16x16x32_bf16(xh1.v, wh1, a, 0, 0, 0);
                a = __builtin_amdgcn_mfma_f32_16x16x32_bf16(xl0.v, wh0, a, 0, 0, 0);
                a = __builtin_amdgcn_mfma_f32_16x16x32_bf16(xl1.v, wh1, a, 0, 0, 0);
                a = __builtin_amdgcn_mfma_f32_16x16x32_bf16(xh0.v, wl0, a, 0, 0, 0);
                a = __builtin_amdgcn_mfma_f32_16x16x32_bf16(xh1.v, wl1, a, 0, 0, 0);
            }
            acc[m2] = a;
        }
    }

    if (which < 2) {
        ushort* OH = (ushort*)((char*)ws + (which == 0 ? QHI_B : KHI_B)) + (size_t)bh * T_SEQ * DK;
        ushort* OL = (ushort*)((char*)ws + (which == 0 ? QLO_B : KLO_B)) + (size_t)bh * T_SEQ * DK;
        const float scl = (which == 0) ? QSCALE : 1.0f;
#pragma unroll
        for (int m2 = 0; m2 < 4; ++m2) {
            uint h0, l0, h1, l1;
            tsplit2(acc[m2][0] * scl, acc[m2][1] * scl, h0, l0);
            tsplit2(acc[m2][2] * scl, acc[m2][3] * scl, h1, l1);
            const size_t addr = (size_t)(t0 + w * 16 + lr) * DK + m2 * 16 + lg * 4;
            *(uint2*)&OH[addr] = make_uint2(h0, h1);
            *(uint2*)&OL[addr] = make_uint2(l0, l1);
        }
    } else {
        ushort* OH = (ushort*)((char*)ws + VTHI_B) + (size_t)bh * DK * T_SEQ;
        ushort* OL = (ushort*)((char*)ws + VTLO_B) + (size_t)bh * DK * T_SEQ;
#pragma unroll
        for (int n2 = 0; n2 < 4; ++n2) {
            uint h0, l0, h1, l1;
            tsplit2(acc[n2][0], acc[n2][1], h0, l0);
            tsplit2(acc[n2][2], acc[n2][3], h1, l1);
            const size_t addr = (size_t)(n2 * 16 + lr) * T_SEQ + t0 + w * 16 + lg * 4;
            *(uint2*)&OH[addr] = make_uint2(h0, h1);
            *(uint2*)&OL[addr] = make_uint2(l0, l1);
        }
    }
}

// ---------------------------------------------------------------------------
// Kernel 2: flash attention (round-5 structure, 59.2 us measured @ round 10).
// Split-K over NCH=2 chunks.  grid (T/64, BH, NCH), block 256.
// ---------------------------------------------------------------------------
__global__ __launch_bounds__(256, 2) void attn_fwd(
    const int* __restrict__ ls_ptr, float* __restrict__ ws)
{
    const int bh = blockIdx.y, b = bh >> 3, h = bh & 7;
    const int mtype = h >> 1;
    const int row0 = blockIdx.x * 64, rb = row0 >> 6;
    const int chunk = blockIdx.z;
    const int ls = *ls_ptr;

    float* mrow = (float*)((char*)ws + MST_B) + ((size_t)chunk * BH + bh) * T_SEQ;
    float* lrow = (float*)((char*)ws + LST_B) + ((size_t)chunk * BH + bh) * T_SEQ;

    int klo = 0, khi = NKB - 1;
    if (mtype == 1) {
        int l2 = row0 - ls; if (l2 < 0) l2 = 0;
        int h2 = row0 + 63 + ls; if (h2 > T_SEQ - 1) h2 = T_SEQ - 1;
        klo = l2 >> 6; khi = h2 >> 6;
    } else if (mtype == 2) {
        klo = rb;
    } else if (mtype == 3) {
        khi = rb;
    }
    const int kb0 = klo > chunk * CHB ? klo : chunk * CHB;
    const int kb1 = khi < chunk * CHB + CHB - 1 ? khi : chunk * CHB + CHB - 1;

    const int tid = threadIdx.x;
    if (kb0 > kb1) {
        if (tid < 64) { mrow[row0 + tid] = -INFINITY; lrow[row0 + tid] = 0.f; }
        return;
    }

    const ushort* Qh_g = (const ushort*)((char*)ws + QHI_B) + (size_t)bh * T_SEQ * DK;
    const ushort* Ql_g = (const ushort*)((char*)ws + QLO_B) + (size_t)bh * T_SEQ * DK;
    const ushort* Kh_g = (const ushort*)((char*)ws + KHI_B) + (size_t)bh * T_SEQ * DK;
    const ushort* Kl_g = (const ushort*)((char*)ws + KLO_B) + (size_t)bh * T_SEQ * DK;
    const ushort* Vh_g = (const ushort*)((char*)ws + VTHI_B) + (size_t)bh * DK * T_SEQ;
    const ushort* Vl_g = (const ushort*)((char*)ws + VTLO_B) + (size_t)bh * DK * T_SEQ;
    float* attP = (float*)((char*)ws + ATTP_B) + (size_t)chunk * CHUNK_F;

    __shared__ ushort KhS[64][64], KlS[64][64];
    __shared__ ushort VhS[64][64], VlS[64][64];
    __shared__ ushort PhS[64][64], PlS[64][64];

    const int lane = tid & 63, w = tid >> 6;
    const int lr = lane & 15, lg = lane >> 4;
    const int sg = tid & 7, srow = tid >> 3;
    const int swz0 = (sg ^ (srow & 7)) * 8;
    const int c0s = (lg ^ (lr & 7)) * 8, c1s = c0s ^ 32;

    // Q fragments (loop-invariant, from global)
    const ushort* qh = Qh_g + (size_t)(row0 + w * 16 + lr) * DK;
    const ushort* ql = Ql_g + (size_t)(row0 + w * 16 + lr) * DK;
    const bf16x8 bqh0 = *(const bf16x8*)(qh + lg * 8);
    const bf16x8 bqh1 = *(const bf16x8*)(qh + 32 + lg * 8);
    const bf16x8 bql0 = *(const bf16x8*)(ql + lg * 8);
    const bf16x8 bql1 = *(const bf16x8*)(ql + 32 + lg * 8);

    float m_i = -INFINITY, l_i = 0.f;
    f32x4 oacc[4];
#pragma unroll
    for (int i = 0; i < 4; ++i) oacc[i] = (f32x4){0.f, 0.f, 0.f, 0.f};

    uint4 kr0, kr1, kr2, kr3, vr0, vr1, vr2, vr3;
    kr0 = *(const uint4*)&Kh_g[(size_t)(kb0 * 64 + srow) * DK + sg * 8];
    kr1 = *(const uint4*)&Kh_g[(size_t)(kb0 * 64 + srow + 32) * DK + sg * 8];
    kr2 = *(const uint4*)&Kl_g[(size_t)(kb0 * 64 + srow) * DK + sg * 8];
    kr3 = *(const uint4*)&Kl_g[(size_t)(kb0 * 64 + srow + 32) * DK + sg * 8];
    vr0 = *(const uint4*)&Vh_g[(size_t)srow * T_SEQ + kb0 * 64 + sg * 8];
    vr1 = *(const uint4*)&Vh_g[(size_t)(srow + 32) * T_SEQ + kb0 * 64 + sg * 8];
    vr2 = *(const uint4*)&Vl_g[(size_t)srow * T_SEQ + kb0 * 64 + sg * 8];
    vr3 = *(const uint4*)&Vl_g[(size_t)(srow + 32) * T_SEQ + kb0 * 64 + sg * 8];

    for (int kb = kb0; kb <= kb1; ++kb) {
        __syncthreads();
        *(uint4*)&KhS[srow][swz0] = kr0; *(uint4*)&KhS[srow + 32][swz0] = kr1;
        *(uint4*)&KlS[srow][swz0] = kr2; *(uint4*)&KlS[srow + 32][swz0] = kr3;
        *(uint4*)&VhS[srow][swz0] = vr0; *(uint4*)&VhS[srow + 32][swz0] = vr1;
        *(uint4*)&VlS[srow][swz0] = vr2; *(uint4*)&VlS[srow + 32][swz0] = vr3;
        if (kb < kb1) {
            const int kn = kb + 1;
            kr0 = *(const uint4*)&Kh_g[(size_t)(kn * 64 + srow) * DK + sg * 8];
            kr1 = *(const uint4*)&Kh_g[(size_t)(kn * 64 + srow + 32) * DK + sg * 8];
            kr2 = *(const uint4*)&Kl_g[(size_t)(kn * 64 + srow) * DK + sg * 8];
            kr3 = *(const uint4*)&Kl_g[(size_t)(kn * 64 + srow + 32) * DK + sg * 8];
            vr0 = *(const uint4*)&Vh_g[(size_t)srow * T_SEQ + kn * 64 + sg * 8];
            vr1 = *(const uint4*)&Vh_g[(size_t)(srow + 32) * T_SEQ + kn * 64 + sg * 8];
            vr2 = *(const uint4*)&Vl_g[(size_t)srow * T_SEQ + kn * 64 + sg * 8];
            vr3 = *(const uint4*)&Vl_g[(size_t)(srow + 32) * T_SEQ + kn * 64 + sg * 8];
        }
        __syncthreads();

        // ---- QK: S^T[s][t] = K . Q^T ----
        f32x4 sacc[4];
#pragma unroll
        for (int m = 0; m < 4; ++m) {
            const int row = m * 16 + lr;
            bf16x8 ah0 = *(const bf16x8*)&KhS[row][c0s];
            bf16x8 ah1 = *(const bf16x8*)&KhS[row][c1s];
            bf16x8 al0 = *(const bf16x8*)&KlS[row][c0s];
            bf16x8 al1 = *(const bf16x8*)&KlS[row][c1s];
            f32x4 a = (f32x4){0.f, 0.f, 0.f, 0.f};
            a = __builtin_amdgcn_mfma_f32_16x16x32_bf16(ah0, bqh0, a, 0, 0, 0);
            a = __builtin_amdgcn_mfma_f32_16x16x32_bf16(ah1, bqh1, a, 0, 0, 0);
            a = __builtin_amdgcn_mfma_f32_16x16x32_bf16(ah0, bql0, a, 0, 0, 0);
            a = __builtin_amdgcn_mfma_f32_16x16x32_bf16(ah1, bql1, a, 0, 0, 0);
            a = __builtin_amdgcn_mfma_f32_16x16x32_bf16(al0, bqh0, a, 0, 0, 0);
            a = __builtin_amdgcn_mfma_f32_16x16x32_bf16(al1, bqh1, a, 0, 0, 0);
            sacc[m] = a;
        }

        // ---- mask + online softmax (base 2; t = lane&15) ----
        const int t_glob = row0 + w * 16 + lr;
        const bool needmask = (mtype == 1) || ((mtype >= 2) && (kb == rb));
        float p[4][4];
        float vmax = -INFINITY;
#pragma unroll
        for (int m = 0; m < 4; ++m)
#pragma unroll
            for (int r = 0; r < 4; ++r) {
                float x = sacc[m][r];
                if (needmask) {
                    int s_glob = kb * 64 + m * 16 + lg * 4 + r;
                    bool keep;
                    if (mtype == 1) keep = (t_glob - s_glob <= ls) && (s_glob - t_glob <= ls);
                    else if (mtype == 2) keep = (s_glob >= t_glob);
                    else keep = (s_glob <= t_glob);
                    if (!keep) x = -INFINITY;
                }
                p[m][r] = x;
                vmax = fmaxf(vmax, x);
            }
        vmax = fmaxf(vmax, __shfl_xor(vmax, 16, 64));
        vmax = fmaxf(vmax, __shfl_xor(vmax, 32, 64));
        const float mn = fmaxf(m_i, vmax);
        float factor = 1.f, psum = 0.f;
        if (mn == -INFINITY) {
#pragma unroll
            for (int m = 0; m < 4; ++m)
#pragma unroll
                for (int r = 0; r < 4; ++r) p[m][r] = 0.f;
        } else {
            factor = exp2f(m_i - mn);
            m_i = mn;
#pragma unroll
            for (int m = 0; m < 4; ++m)
#pragma unroll
                for (int r = 0; r < 4; ++r) {
                    p[m][r] = exp2f(p[m][r] - mn);
                    psum += p[m][r];
                }
        }
        psum += __shfl_xor(psum, 16, 64);
        psum += __shfl_xor(psum, 32, 64);
        l_i = l_i * factor + psum;

        // ---- store P (t-major, swizzled) ----
#pragma unroll
        for (int m = 0; m < 4; ++m) {
            uint ph01, pl01, ph23, pl23;
            tsplit2(p[m][0], p[m][1], ph01, pl01);
            tsplit2(p[m][2], p[m][3], ph23, pl23);
            const int pg = (((m * 2 + (lg >> 1)) ^ (lr & 7)) * 8) + (lg & 1) * 4;
            *(uint2*)&PhS[w * 16 + lr][pg] = make_uint2(ph01, ph23);
            *(uint2*)&PlS[w * 16 + lr][pg] = make_uint2(pl01, pl23);
        }

        // ---- rescale O ----
        float fr[4];
#pragma unroll
        for (int r = 0; r < 4; ++r) fr[r] = __shfl(factor, lg * 4 + r, 64);
#pragma unroll
        for (int n2 = 0; n2 < 4; ++n2)
#pragma unroll
            for (int r = 0; r < 4; ++r) oacc[n2][r] *= fr[r];

        // ---- PV: O[t][dk] += P V ----
        const bf16x8 aph0 = *(const bf16x8*)&PhS[w * 16 + lr][c0s];
        const bf16x8 aph1 = *(const bf16x8*)&PhS[w * 16 + lr][c1s];
        const bf16x8 apl0 = *(const bf16x8*)&PlS[w * 16 + lr][c0s];
        const bf16x8 apl1 = *(const bf16x8*)&PlS[w * 16 + lr][c1s];
#pragma unroll
        for (int n2 = 0; n2 < 4; ++n2) {
            const int row = n2 * 16 + lr;
            bf16x8 bh0 = *(const bf16x8*)&VhS[row][c0s];
            bf16x8 bh1 = *(const bf16x8*)&VhS[row][c1s];
            bf16x8 bl0 = *(const bf16x8*)&VlS[row][c0s];
            bf16x8 bl1 = *(const bf16x8*)&VlS[row][c1s];
            f32x4 a = oacc[n2];
            a = __builtin_amdgcn_mfma_f32_16x16x32_bf16(aph0, bh0, a, 0, 0, 0);
            a = __builtin_amdgcn_mfma_f32_16x16x32_bf16(aph1, bh1, a, 0, 0, 0);
            a = __builtin_amdgcn_mfma_f32_16x16x32_bf16(aph0, bl0, a, 0, 0, 0);
            a = __builtin_amdgcn_mfma_f32_16x16x32_bf16(aph1, bl1, a, 0, 0, 0);
            a = __builtin_amdgcn_mfma_f32_16x16x32_bf16(apl0, bh0, a, 0, 0, 0);
            a = __builtin_amdgcn_mfma_f32_16x16x32_bf16(apl1, bh1, a, 0, 0, 0);
            oacc[n2] = a;
        }
    }

#pragma unroll
    for (int n2 = 0; n2 < 4; ++n2)
#pragma unroll
        for (int r = 0; r < 4; ++r) {
            int t = row0 + w * 16 + lg * 4 + r;
            attP[((size_t)b * T_SEQ + t) * HK + h * DK + n2 * 16 + lr] = oacc[n2][r];
        }
    if (lg == 0) {
        mrow[row0 + w * 16 + lr] = m_i;
        lrow[row0 + w * 16 + lr] = l_i;
    }
}

// ---------------------------------------------------------------------------
// Kernel 3: per-(b,h) reduce of (m,l) over chunks -> scale (base-2 domain).
// ---------------------------------------------------------------------------
__global__ __launch_bounds__(256) void softmax_stats(float* __restrict__ ws)
{
    const int bh = blockIdx.x;
    float* mbase = (float*)((char*)ws + MST_B);
    float* lbase = (float*)((char*)ws + LST_B);
    float* sbase = (float*)((char*)ws + SST_B);

    __shared__ float red[256];
    const int tid = threadIdx.x;
    const int n = NCH * T_SEQ;

    float mymax = -INFINITY;
    for (int i = tid; i < n; i += 256) {
        int c = i >> 11, t = i & 2047;
        mymax = fmaxf(mymax, mbase[((size_t)c * BH + bh) * T_SEQ + t]);
    }
    red[tid] = mymax; __syncthreads();
    for (int s = 128; s > 0; s >>= 1) {
        if (tid < s) red[tid] = fmaxf(red[tid], red[tid + s]);
        __syncthreads();
    }
    const float M = red[0]; __syncthreads();

    float mysum = 0.f;
    for (int i = tid; i < n; i += 256) {
        int c = i >> 11, t = i & 2047;
        size_t idx = ((size_t)c * BH + bh) * T_SEQ + t;
        mysum += lbase[idx] * exp2f(mbase[idx] - M);
    }
    red[tid] = mysum; __syncthreads();
    for (int s = 128; s > 0; s >>= 1) {
        if (tid < s) red[tid] += red[tid + s];
        __syncthreads();
    }
    const float Z = red[0];

    for (int i = tid; i < n; i += 256) {
        int c = i >> 11, t = i & 2047;
        size_t idx = ((size_t)c * BH + bh) * T_SEQ + t;
        sbase[idx] = exp2f(mbase[idx] - M) / Z;
    }
}

// ---------------------------------------------------------------------------
// Kernel 4: FUSED scale-reduce + output GEMM.
// out[bt][d] = sum_hk (sum_c attP[c][bt][hk]*sc[c][b,h,t]) * Wo[hk][d]
// Round-5 out_proj structure (LDS-staged B, grid (D/64, BT/64), 512 blocks);
// only the A-fragment source changes: built in-register from attP + scale.
// ---------------------------------------------------------------------------
__global__ __launch_bounds__(256) void out_fused(
    float* __restrict__ ws, float* __restrict__ out)
{
    const int d0 = blockIdx.x * 64;
    const int r0 = blockIdx.y * 64;           // over B*T
    const int b = r0 >> 11;
    const int t0 = r0 & 2047;
    const float* attP = (const float*)((char*)ws + ATTP_B);
    const float* sc = (const float*)((char*)ws + SST_B);
    const ushort* WoH = (const ushort*)((char*)ws + WOTHI_B);
    const ushort* WoL = (const ushort*)((char*)ws + WOTLO_B);

    __shared__ ushort BsH[64][64], BsL[64][64];

    const int tid = threadIdx.x, lane = tid & 63, w = tid >> 6;
    const int lr = lane & 15, lg = lane >> 4;
    const int sg = tid & 7, srow = tid >> 3;
    const int swz0 = (sg ^ (srow & 7)) * 8;
    const int c0s = (lg ^ (lr & 7)) * 8, c1s = c0s ^ 32;

    const int t_lane = t0 + w * 16 + lr;
    const float* aP = attP + ((size_t)b * T_SEQ + t_lane) * HK;

    f32x4 acc[4];
#pragma unroll
    for (int i = 0; i < 4; ++i) acc[i] = (f32x4){0.f, 0.f, 0.f, 0.f};

    for (int k0 = 0; k0 < HK; k0 += 64) {
        const int h = k0 >> 6;
        __syncthreads();
        *(uint4*)&BsH[srow][swz0]      = *(const uint4*)&WoH[(size_t)(d0 + srow) * HK + k0 + sg * 8];
        *(uint4*)&BsH[srow + 32][swz0] = *(const uint4*)&WoH[(size_t)(d0 + srow + 32) * HK + k0 + sg * 8];
        *(uint4*)&BsL[srow][swz0]      = *(const uint4*)&WoL[(size_t)(d0 + srow) * HK + k0 + sg * 8];
        *(uint4*)&BsL[srow + 32][swz0] = *(const uint4*)&WoL[(size_t)(d0 + srow + 32) * HK + k0 + sg * 8];
        __syncthreads();

        // ---- A-frags: chunk-sum of attP * scale, then split to bf16 hi/lo ----
        const float s0 = sc[((size_t)0 * BH + b * NH + h) * T_SEQ + t_lane];
        const float s1 = sc[((size_t)1 * BH + b * NH + h) * T_SEQ + t_lane];
        union { bf16x8 v; uint u[4]; } ah[2], al[2];
#pragma unroll
        for (int kh = 0; kh < 2; ++kh) {
            const float* p = aP + k0 + kh * 32 + lg * 8;
            float4 x0 = *(const float4*)(p);
            float4 x1 = *(const float4*)(p + 4);
            float4 y0 = *(const float4*)(p + CHUNK_F);
            float4 y1 = *(const float4*)(p + CHUNK_F + 4);
            float v[8];
            v[0] = fmaf(x0.x, s0, y0.x * s1); v[1] = fmaf(x0.y, s0, y0.y * s1);
            v[2] = fmaf(x0.z, s0, y0.z * s1); v[3] = fmaf(x0.w, s0, y0.w * s1);
            v[4] = fmaf(x1.x, s0, y1.x * s1); v[5] = fmaf(x1.y, s0, y1.y * s1);
            v[6] = fmaf(x1.z, s0, y1.z * s1); v[7] = fmaf(x1.w, s0, y1.w * s1);
#pragma unroll
            for (int i = 0; i < 4; ++i)
                tsplit2(v[2 * i], v[2 * i + 1], ah[kh].u[i], al[kh].u[i]);
        }

#pragma unroll
        for (int n2 = 0; n2 < 4; ++n2) {
            const int row = n2 * 16 + lr;
            bf16x8 wh0 = *(const bf16x8*)&BsH[row][c0s];
            bf16x8 wh1 = *(const bf16x8*)&BsH[row][c1s];
            bf16x8 wl0 = *(const bf16x8*)&BsL[row][c0s];
            bf16x8 wl1 = *(const bf16x8*)&BsL[row][c1s];
            f32x4 a = acc[n2];
            a = __builtin_amdgcn_mfma_f32_16x16x32_bf16(ah[0].v, wh0, a, 0, 0, 0);
            a = __builtin_amdgcn_mfma_f32_16x16x32_bf16(ah[1].v, wh1, a, 0, 0, 0);
            a = __builtin_amdgcn_mfma_f32_16x16x32_bf16(ah[0].v, wl0, a, 0, 0, 0);
            a = __builtin_amdgcn_mfma_f32_16x16x32_bf16(ah[1].v, wl1, a, 0, 0, 0);
            a = __builtin_amdgcn_mfma_f32_16x16x32_bf16(al[0].v, wh0, a, 0, 0, 0);
            a = __builtin_amdgcn_mfma_f32_16x16x32_bf16(al[1].v, wh1, a, 0, 0, 0);
            acc[n2] = a;
        }
    }

#pragma unroll
    for (int n2 = 0; n2 < 4; ++n2)
#pragma unroll
        for (int i = 0; i < 4; ++i)
            out[(size_t)(r0 + w * 16 + lg * 4 + i) * D_MODEL + d0 + n2 * 16 + lr] = acc[n2][i];
}

// ---------------------------------------------------------------------------
extern "C" void kernel_launch(void* const* d_in, const int* in_sizes, int n_in,
                              void* d_out, int out_size, void* d_ws, size_t ws_size,
                              hipStream_t stream)
{
    const float* query = (const float*)d_in[0];
    const float* value = (const float*)d_in[1];
    const float* Wq = (const float*)d_in[2];
    const float* Wk = (const float*)d_in[3];
    const float* Wv = (const float*)d_in[4];
    const float* Wo = (const float*)d_in[5];
    const int* ls = (const int*)d_in[6];
    float* out = (float*)d_out;
    float* ws = (float*)d_ws;

    split_w<<<dim3(2048), 256, 0, stream>>>(Wq, Wk, Wv, Wo, ws);

    proj_mfma<<<dim3(T_SEQ / 64, BH, 3), 256, 0, stream>>>(query, value, ws);

    attn_fwd<<<dim3(T_SEQ / 64, BH, NCH), 256, 0, stream>>>(ls, ws);

    softmax_stats<<<dim3(BH), 256, 0, stream>>>(ws);

    out_fused<<<dim3(D_MODEL / 64, 2 * T_SEQ / 64), 256, 0, stream>>>(ws, out);
}